// Round 3
// baseline (304.920 us; speedup 1.0000x reference)
//
#include <hip/hip_runtime.h>
#include <math.h>

// ---------------- workspace layout (float offsets) ----------------
#define WS_E0   0       // E_s[19]
#define WS_E1   19      // E_t[19]
#define WS_G0   64      // G_s[361] (i<=j)
#define WS_G1   448     // G_t[361]
#define WS_Z    1152    // row sumexp [304]
#define WS_WBF  2048    // conv_w as bf16 [768*128] = 49152 floats
#define WS_PIX  51200   // per-pixel partials [2 halves][34304 px][4]
#define PIXHALF 137216  // 34304*4 floats per half

typedef __bf16 bf16x8 __attribute__((ext_vector_type(8)));
typedef float  f32x4  __attribute__((ext_vector_type(4)));

// ---------------- init: zero accumulators + convert W to bf16 ----------------
// grid 64 x 256
__global__ void k_init(const float* __restrict__ conv_w, float* __restrict__ ws,
                       float* __restrict__ out) {
    int gid = blockIdx.x * 256 + threadIdx.x;
    __bf16* Wb = (__bf16*)(ws + WS_WBF);
    #pragma unroll
    for (int j = 0; j < 6; j++) {
        int idx = gid + j * 16384;       // 98304 = 16384*6 exact
        Wb[idx] = (__bf16)conv_w[idx];
    }
    if (blockIdx.x == 0) {
        for (int k = (int)threadIdx.x; k < 2048; k += 256) ws[k] = 0.f;
        if (threadIdx.x < 2) out[threadIdx.x] = 0.f;
    }
}

// ---------------- bilinear sample of t_logit row (65x65 -> 129x129) ----------------
__device__ __forceinline__ float t_resized(const float* __restrict__ Trow, int k) {
    int y = k / 129, x = k - y * 129;
    int y0 = y >> 1, x0 = x >> 1;
    int y1 = y0 + (y & 1), x1 = x0 + (x & 1);
    float fy = 0.5f * (float)(y & 1), fx = 0.5f * (float)(x & 1);
    float v00 = Trow[y0 * 65 + x0], v01 = Trow[y0 * 65 + x1];
    float v10 = Trow[y1 * 65 + x0], v11 = Trow[y1 * 65 + x1];
    float r0 = v00 + fx * (v01 - v00);
    float r1 = v10 + fx * (v11 - v10);
    return r0 + fy * (r1 - r0);
}

// ---------------- fused main: pi partials (blocks 0..1071) + rowstats (1072..1375) ----
// pi role: (b,tile) x half; 6 chunks of 64 channels; wave = 16 channels/chunk.
// t_out staged via coalesced float4 -> per-wave LDS tile, register-prefetched
// one chunk ahead so HBM latency hides behind MFMA+epilogue.
__launch_bounds__(256, 4)
__global__ void k_main(const float* __restrict__ s_out, const float* __restrict__ t_out,
                       const float* __restrict__ bias,
                       const float* __restrict__ s_logit, const float* __restrict__ t_logit,
                       float* __restrict__ ws, float* __restrict__ out) {
    __shared__ __align__(16) char lds[17408];
    const int tid = threadIdx.x;
    const int bx  = blockIdx.x;

    if (bx < 1072) {
        __bf16* xs    = (__bf16*)lds;     // 64px x 136c bf16 (resize out / B-frag src)
        float*  tbase = (float*)lds;      // then: 4 waves x (16 x 68) t-tiles
        float*  scr   = (float*)lds;      // then: 64 x 68 merge scratch

        const int half = bx & 1;
        const int bt   = bx >> 1;
        const int b    = bt / 67;
        const int tile = bt - b * 67;
        const int hw0  = tile * 64;
        const bool tail = (tile == 66);

        // ---- bilinear resize 33x33 -> 65x65 tile into xs[px][c] ----
        {
            const float* Sb = s_out + b * 128 * 1089;
            #pragma unroll
            for (int ii = 0; ii < 32; ii++) {
                int idx = tid + ii * 256;
                int c = idx >> 6, px = idx & 63;
                int hw = hw0 + px;
                float v = 0.f;
                if (hw < 4225) {
                    int h = hw / 65, w = hw - h * 65;
                    int y0 = h >> 1, x0 = w >> 1;
                    int y1 = y0 + (h & 1), x1 = x0 + (w & 1);
                    float wy = 0.5f * (float)(h & 1), wx = 0.5f * (float)(w & 1);
                    const float* Sc = Sb + c * 1089;
                    float v00 = Sc[y0 * 33 + x0], v01 = Sc[y0 * 33 + x1];
                    float v10 = Sc[y1 * 33 + x0], v11 = Sc[y1 * 33 + x1];
                    float r0 = v00 + wx * (v01 - v00);
                    float r1 = v10 + wx * (v11 - v10);
                    v = r0 + wy * (r1 - r0);
                }
                xs[px * 136 + c] = (__bf16)v;
            }
        }
        __syncthreads();

        const int l = tid & 63, wv = tid >> 6, q = l >> 4, n = l & 15;

        // ---- B fragments once ----
        bf16x8 bfrag[4][4];
        #pragma unroll
        for (int pt = 0; pt < 4; pt++)
            #pragma unroll
            for (int kf = 0; kf < 4; kf++)
                bfrag[pt][kf] = *(const bf16x8*)&xs[(pt * 16 + n) * 136 + kf * 32 + q * 8];
        __syncthreads();   // xs dead; region becomes t-tiles

        const __bf16* Wbf = (const __bf16*)(ws + WS_WBF);
        float* tst = tbase + wv * 1088;    // this wave's 16x68 tile

        float Zt[4], St[4], Dd[4], Zs[4];
        #pragma unroll
        for (int pt = 0; pt < 4; pt++) { Zt[pt] = 0.f; St[pt] = 0.f; Dd[pt] = 0.f; Zs[pt] = 0.f; }

        float4 t4[4];
        auto load_t = [&](int ch, float4* dst) {
            const float* tb = t_out + (size_t)(b * 768 + ch * 64 + wv * 16) * 4225;
            #pragma unroll
            for (int ii = 0; ii < 4; ii++) {
                int lin = ii * 64 + l;
                int row = lin >> 4, p4 = lin & 15;
                if (!tail) {
                    dst[ii] = *(const float4*)(tb + row * 4225 + hw0 + p4 * 4);
                } else {
                    const float* rr = tb + row * 4225;
                    int b0 = hw0 + p4 * 4;
                    float4 v;
                    v.x = rr[min(b0 + 0, 4224)];
                    v.y = rr[min(b0 + 1, 4224)];
                    v.z = rr[min(b0 + 2, 4224)];
                    v.w = rr[min(b0 + 3, 4224)];
                    dst[ii] = v;
                }
            }
        };
        load_t(half * 6, t4);

        for (int c6 = 0; c6 < 6; c6++) {
            const int ch  = half * 6 + c6;
            const int ob  = ch * 64 + wv * 16;
            const int o_r = ob + q * 4;

            // stage this chunk's t-tile (per-wave region, no barrier needed)
            #pragma unroll
            for (int ii = 0; ii < 4; ii++) {
                int lin = ii * 64 + l;
                int row = lin >> 4, p4 = lin & 15;
                *(float4*)(tst + row * 68 + p4 * 4) = t4[ii];
            }

            // A frags (pre-converted bf16 W) + bias
            bf16x8 afrag[4];
            const __bf16* Wr = Wbf + (size_t)(ob + n) * 128 + q * 8;
            #pragma unroll
            for (int kf = 0; kf < 4; kf++)
                afrag[kf] = *(const bf16x8*)(Wr + kf * 32);
            f32x4 bq = *(const f32x4*)&bias[o_r];

            // prefetch next chunk's t into registers (in flight across MFMA+epilogue)
            float4 t4n[4];
            const bool pf = (c6 < 5);
            if (pf) load_t(ch + 1, t4n);

            // 16 MFMA
            f32x4 acc[4];
            #pragma unroll
            for (int pt = 0; pt < 4; pt++) {
                f32x4 a0 = {0.f, 0.f, 0.f, 0.f};
                #pragma unroll
                for (int kf = 0; kf < 4; kf++)
                    a0 = __builtin_amdgcn_mfma_f32_16x16x32_bf16(afrag[kf], bfrag[pt][kf], a0, 0, 0, 0);
                acc[pt] = a0;
            }

            // epilogue: D[row=q*4+r][col=pt*16+n]; linear exp accumulators
            #pragma unroll
            for (int pt = 0; pt < 4; pt++) {
                #pragma unroll
                for (int r = 0; r < 4; r++) {
                    float tv  = tst[(q * 4 + r) * 68 + pt * 16 + n];
                    float s1v = acc[pt][r] + bq[r];
                    float e   = __expf(tv);
                    Zt[pt] += e;
                    St[pt]  = fmaf(e, tv,  St[pt]);
                    Dd[pt]  = fmaf(e, s1v, Dd[pt]);
                    Zs[pt] += __expf(s1v);
                }
            }

            if (pf) {
                #pragma unroll
                for (int ii = 0; ii < 4; ii++) t4[ii] = t4n[ii];
            }
        }

        // ---- merge 16 partitions per pixel, write per-pixel partials ----
        __syncthreads();
        {
            int part = wv * 4 + q;
            #pragma unroll
            for (int pt = 0; pt < 4; pt++) {
                f32x4 v = {Zt[pt], St[pt], Dd[pt], Zs[pt]};
                *(f32x4*)&scr[(pt * 16 + n) * 68 + part * 4] = v;
            }
        }
        __syncthreads();
        if (tid < 64) {
            float Z = 0.f, S = 0.f, D = 0.f, Z2 = 0.f;
            #pragma unroll
            for (int p = 0; p < 16; p++) {
                const float* s4 = &scr[tid * 68 + p * 4];
                Z += s4[0]; S += s4[1]; D += s4[2]; Z2 += s4[3];
            }
            f32x4 v = {Z, S, D, Z2};
            *(f32x4*)&ws[WS_PIX + half * PIXHALF + ((size_t)b * 4288 + tile * 64 + tid) * 4] = v;
        }
    } else {
        // ---- rowstats role ----
        float* red = (float*)lds;
        int row  = bx - 1072;
        int side = (row >= 152) ? 1 : 0;
        int r    = side ? row - 152 : row;
        const float* src = side ? (t_logit + r * 4225) : (s_logit + r * 16641);

        float z = 0.f, s = 0.f;
        for (int k = tid; k < 16641; k += 256) {
            float v = side ? t_resized(src, k) : src[k];
            float e = __expf(v);
            z += e;
            s = fmaf(e, v, s);
        }
        for (int off = 32; off > 0; off >>= 1) { z += __shfl_down(z, off); s += __shfl_down(s, off); }
        if ((tid & 63) == 0) { red[tid >> 6] = z; red[4 + (tid >> 6)] = s; }
        __syncthreads();
        if (tid == 0) {
            float Z = red[0] + red[1] + red[2] + red[3];
            float S = red[4] + red[5] + red[6] + red[7];
            ws[WS_Z + row] = Z;
            atomicAdd(&ws[(side ? WS_E1 : WS_E0) + (r % 19)], S / Z - logf(Z));
        }
    }
}

// ---------------- mid: Gram (blocks 0..527) + pi finalize (528..661) ----------------
#define KT 512
#define KP 516
__global__ void k_mid(const float* __restrict__ s_logit, const float* __restrict__ t_logit,
                      float* __restrict__ ws, float* __restrict__ out) {
    __shared__ __align__(16) char lds[39296];
    const int tid = threadIdx.x;
    const int bx  = blockIdx.x;

    if (bx < 528) {
        float* pbuf  = (float*)lds;
        float* rowiz = (float*)(lds + 39216);
        int side = (bx >= 264) ? 1 : 0;
        int rm   = side ? bx - 264 : bx;
        int b = rm / 33, kt = rm - b * 33;
        int k0 = kt * KT;

        if (tid < 19) rowiz[tid] = 1.0f / ws[WS_Z + side * 152 + b * 19 + tid];
        __syncthreads();

        for (int i = 0; i < 19; i++) {
            const float* src = side ? (t_logit + (b * 19 + i) * 4225) : (s_logit + (b * 19 + i) * 16641);
            float iz = rowiz[i];
            for (int kl = tid; kl < KT; kl += 256) {
                int k = k0 + kl;
                float p = 0.f;
                if (k < 16641) {
                    float v = side ? t_resized(src, k) : src[k];
                    p = __expf(v) * iz;
                }
                pbuf[i * KP + kl] = p;
            }
        }
        __syncthreads();

        if (tid < 190) {
            int t = tid, i = 0;
            while (t >= 19 - i) { t -= 19 - i; i++; }
            int j = i + t;
            const float* pi_ = &pbuf[i * KP];
            const float* pj_ = &pbuf[j * KP];
            float g = 0.f;
            #pragma unroll 4
            for (int kl = 0; kl < KT; kl += 4) {
                float4 a = *(const float4*)&pi_[kl];
                float4 c = *(const float4*)&pj_[kl];
                g = fmaf(a.x, c.x, g); g = fmaf(a.y, c.y, g);
                g = fmaf(a.z, c.z, g); g = fmaf(a.w, c.w, g);
            }
            atomicAdd(&ws[(side ? WS_G1 : WS_G0) + i * 19 + j], g);
        }
    } else {
        // pi finalize: one thread per padded pixel
        float* red = (float*)lds;
        int gp = (bx - 528) * 256 + tid;      // 0..34303
        int b  = gp / 4288;
        int tp = gp - b * 4288;
        f32x4 a = *(const f32x4*)&ws[WS_PIX + (size_t)gp * 4];
        f32x4 c = *(const f32x4*)&ws[WS_PIX + PIXHALF + (size_t)gp * 4];
        float Z = a[0] + c[0], S = a[1] + c[1], D = a[2] + c[2], Z2 = a[3] + c[3];
        float contrib = (tp < 4225) ? ((S - D) / Z - logf(Z) + logf(Z2)) : 0.f;
        for (int off = 32; off > 0; off >>= 1) contrib += __shfl_down(contrib, off);
        if ((tid & 63) == 0) red[tid >> 6] = contrib;
        __syncthreads();
        if (tid == 0)
            atomicAdd(out, (red[0] + red[1] + red[2] + red[3]) * (1.0f / 25958400.0f));
    }
}

// ---------------- finalize lo_loss (1 block, 384 threads) ----------------
__global__ void k_final(const float* __restrict__ ws, float* __restrict__ out) {
    __shared__ float Ms[361], Mt[361], ns[19], nt[19];
    __shared__ float red[8];
    int tid = threadIdx.x;
    if (tid < 361) {
        int i = tid / 19, j = tid - i * 19;
        int lo = min(i, j), hi = max(i, j);
        Ms[tid] = (ws[WS_E0 + hi] - ws[WS_G0 + lo * 19 + hi]) * 0.125f;
        Mt[tid] = (ws[WS_E1 + hi] - ws[WS_G1 + lo * 19 + hi]) * 0.125f;
    }
    __syncthreads();
    if (tid < 19) {
        float as = 0.f, at = 0.f;
        for (int j = 0; j < 19; j++) {
            as = fmaf(Ms[tid * 19 + j], Ms[tid * 19 + j], as);
            at = fmaf(Mt[tid * 19 + j], Mt[tid * 19 + j], at);
        }
        ns[tid] = fmaxf(sqrtf(as), 1e-12f);
        nt[tid] = fmaxf(sqrtf(at), 1e-12f);
    }
    __syncthreads();
    float d = 0.f;
    if (tid < 361) {
        int i = tid / 19;
        float v = Ms[tid] / ns[i] - Mt[tid] / nt[i];
        d = v * v;
    }
    for (int off = 32; off > 0; off >>= 1) d += __shfl_down(d, off);
    if ((tid & 63) == 0) red[tid >> 6] = d;
    __syncthreads();
    if (tid == 0) out[1] = red[0] + red[1] + red[2] + red[3] + red[4] + red[5];
}

extern "C" void kernel_launch(void* const* d_in, const int* in_sizes, int n_in,
                              void* d_out, int out_size, void* d_ws, size_t ws_size,
                              hipStream_t stream) {
    const float* s_out   = (const float*)d_in[0];
    const float* t_out   = (const float*)d_in[1];
    const float* t_logit = (const float*)d_in[2];
    const float* s_logit = (const float*)d_in[3];
    const float* conv_w  = (const float*)d_in[4];
    const float* conv_b  = (const float*)d_in[5];
    float* out = (float*)d_out;
    float* ws  = (float*)d_ws;

    k_init<<<dim3(64), dim3(256), 0, stream>>>(conv_w, ws, out);
    k_main<<<dim3(1376), dim3(256), 0, stream>>>(s_out, t_out, conv_b, s_logit, t_logit, ws, out);
    k_mid<<<dim3(662), dim3(256), 0, stream>>>(s_logit, t_logit, ws, out);
    k_final<<<dim3(1), dim3(384), 0, stream>>>(ws, out);
}

// Round 4
// 276.703 us; speedup vs baseline: 1.1020x; 1.1020x over previous
//
#include <hip/hip_runtime.h>
#include <math.h>

// ---------------- workspace layout (float offsets) ----------------
#define WS_E0   0       // E_s[19]
#define WS_E1   19      // E_t[19]
#define WS_G0   64      // G_s[361] (i<=j)
#define WS_G1   448     // G_t[361]
#define WS_Z    1152    // row sumexp [304]
#define WS_WBF  2048    // conv_w as bf16 [768*128] = 49152 floats
#define WS_PIX  51200   // per-pixel partials [2 halves][34304 px][4]
#define PIXHALF 137216  // 34304*4 floats per half

typedef __bf16 bf16x8 __attribute__((ext_vector_type(8)));
typedef float  f32x4  __attribute__((ext_vector_type(4)));

// ---------------- init: zero accumulators + convert W to bf16 ----------------
// grid 64 x 256
__global__ void k_init(const float* __restrict__ conv_w, float* __restrict__ ws,
                       float* __restrict__ out) {
    int gid = blockIdx.x * 256 + threadIdx.x;
    __bf16* Wb = (__bf16*)(ws + WS_WBF);
    #pragma unroll
    for (int j = 0; j < 6; j++) {
        int idx = gid + j * 16384;       // 98304 = 16384*6 exact
        Wb[idx] = (__bf16)conv_w[idx];
    }
    if (blockIdx.x == 0) {
        for (int k = (int)threadIdx.x; k < 2048; k += 256) ws[k] = 0.f;
        if (threadIdx.x < 2) out[threadIdx.x] = 0.f;
    }
}

// ---------------- bilinear sample of t_logit row (65x65 -> 129x129) ----------------
__device__ __forceinline__ float t_resized(const float* __restrict__ Trow, int k) {
    int y = k / 129, x = k - y * 129;
    int y0 = y >> 1, x0 = x >> 1;
    int y1 = y0 + (y & 1), x1 = x0 + (x & 1);
    float fy = 0.5f * (float)(y & 1), fx = 0.5f * (float)(x & 1);
    float v00 = Trow[y0 * 65 + x0], v01 = Trow[y0 * 65 + x1];
    float v10 = Trow[y1 * 65 + x0], v11 = Trow[y1 * 65 + x1];
    float r0 = v00 + fx * (v01 - v00);
    float r1 = v10 + fx * (v11 - v10);
    return r0 + fy * (r1 - r0);
}

// ---------------- fused main: pi partials (blocks 0..1071) + rowstats (1072..1375) ----
// pi role: (b,tile) x half; 6 chunks of 64 channels; wave = 16 channels/chunk.
// t_out staged via coalesced float4 -> per-wave LDS tile, register-prefetched
// one chunk ahead so HBM latency hides behind MFMA+epilogue.
// launch_bounds(256,2): round-3's (256,4) forced 64 VGPRs -> 50 MB scratch
// spill per dispatch. ~120 VGPRs needed; (256,2) allocates naturally.
__launch_bounds__(256, 2)
__global__ void k_main(const float* __restrict__ s_out, const float* __restrict__ t_out,
                       const float* __restrict__ bias,
                       const float* __restrict__ s_logit, const float* __restrict__ t_logit,
                       float* __restrict__ ws, float* __restrict__ out) {
    __shared__ __align__(16) char lds[17408];
    const int tid = threadIdx.x;
    const int bx  = blockIdx.x;

    if (bx < 1072) {
        __bf16* xs    = (__bf16*)lds;     // 64px x 136c bf16 (resize out / B-frag src)
        float*  tbase = (float*)lds;      // then: 4 waves x (16 x 68) t-tiles
        float*  scr   = (float*)lds;      // then: 64 x 68 merge scratch

        const int half = bx & 1;
        const int bt   = bx >> 1;
        const int b    = bt / 67;
        const int tile = bt - b * 67;
        const int hw0  = tile * 64;
        const bool tail = (tile == 66);

        // ---- bilinear resize 33x33 -> 65x65 tile into xs[px][c] ----
        {
            const float* Sb = s_out + b * 128 * 1089;
            #pragma unroll
            for (int ii = 0; ii < 32; ii++) {
                int idx = tid + ii * 256;
                int c = idx >> 6, px = idx & 63;
                int hw = hw0 + px;
                float v = 0.f;
                if (hw < 4225) {
                    int h = hw / 65, w = hw - h * 65;
                    int y0 = h >> 1, x0 = w >> 1;
                    int y1 = y0 + (h & 1), x1 = x0 + (w & 1);
                    float wy = 0.5f * (float)(h & 1), wx = 0.5f * (float)(w & 1);
                    const float* Sc = Sb + c * 1089;
                    float v00 = Sc[y0 * 33 + x0], v01 = Sc[y0 * 33 + x1];
                    float v10 = Sc[y1 * 33 + x0], v11 = Sc[y1 * 33 + x1];
                    float r0 = v00 + wx * (v01 - v00);
                    float r1 = v10 + wx * (v11 - v10);
                    v = r0 + wy * (r1 - r0);
                }
                xs[px * 136 + c] = (__bf16)v;
            }
        }
        __syncthreads();

        const int l = tid & 63, wv = tid >> 6, q = l >> 4, n = l & 15;

        // ---- B fragments once ----
        bf16x8 bfrag[4][4];
        #pragma unroll
        for (int pt = 0; pt < 4; pt++)
            #pragma unroll
            for (int kf = 0; kf < 4; kf++)
                bfrag[pt][kf] = *(const bf16x8*)&xs[(pt * 16 + n) * 136 + kf * 32 + q * 8];
        __syncthreads();   // xs dead; region becomes t-tiles

        const __bf16* Wbf = (const __bf16*)(ws + WS_WBF);
        float* tst = tbase + wv * 1088;    // this wave's 16x68 tile

        float Zt[4], St[4], Dd[4], Zs[4];
        #pragma unroll
        for (int pt = 0; pt < 4; pt++) { Zt[pt] = 0.f; St[pt] = 0.f; Dd[pt] = 0.f; Zs[pt] = 0.f; }

        float4 t4[4];
        auto load_t = [&](int ch, float4* dst) {
            const float* tb = t_out + (size_t)(b * 768 + ch * 64 + wv * 16) * 4225;
            #pragma unroll
            for (int ii = 0; ii < 4; ii++) {
                int lin = ii * 64 + l;
                int row = lin >> 4, p4 = lin & 15;
                if (!tail) {
                    dst[ii] = *(const float4*)(tb + row * 4225 + hw0 + p4 * 4);
                } else {
                    const float* rr = tb + row * 4225;
                    int b0 = hw0 + p4 * 4;
                    float4 v;
                    v.x = rr[min(b0 + 0, 4224)];
                    v.y = rr[min(b0 + 1, 4224)];
                    v.z = rr[min(b0 + 2, 4224)];
                    v.w = rr[min(b0 + 3, 4224)];
                    dst[ii] = v;
                }
            }
        };
        load_t(half * 6, t4);

        for (int c6 = 0; c6 < 6; c6++) {
            const int ch  = half * 6 + c6;
            const int ob  = ch * 64 + wv * 16;
            const int o_r = ob + q * 4;

            // stage this chunk's t-tile (per-wave region, no barrier needed)
            #pragma unroll
            for (int ii = 0; ii < 4; ii++) {
                int lin = ii * 64 + l;
                int row = lin >> 4, p4 = lin & 15;
                *(float4*)(tst + row * 68 + p4 * 4) = t4[ii];
            }

            // A frags (pre-converted bf16 W) + bias
            bf16x8 afrag[4];
            const __bf16* Wr = Wbf + (size_t)(ob + n) * 128 + q * 8;
            #pragma unroll
            for (int kf = 0; kf < 4; kf++)
                afrag[kf] = *(const bf16x8*)(Wr + kf * 32);
            f32x4 bq = *(const f32x4*)&bias[o_r];

            // prefetch next chunk's t into registers (in flight across MFMA+epilogue)
            float4 t4n[4];
            const bool pf = (c6 < 5);
            if (pf) load_t(ch + 1, t4n);

            // 16 MFMA
            f32x4 acc[4];
            #pragma unroll
            for (int pt = 0; pt < 4; pt++) {
                f32x4 a0 = {0.f, 0.f, 0.f, 0.f};
                #pragma unroll
                for (int kf = 0; kf < 4; kf++)
                    a0 = __builtin_amdgcn_mfma_f32_16x16x32_bf16(afrag[kf], bfrag[pt][kf], a0, 0, 0, 0);
                acc[pt] = a0;
            }

            // epilogue: D[row=q*4+r][col=pt*16+n]; linear exp accumulators
            #pragma unroll
            for (int pt = 0; pt < 4; pt++) {
                #pragma unroll
                for (int r = 0; r < 4; r++) {
                    float tv  = tst[(q * 4 + r) * 68 + pt * 16 + n];
                    float s1v = acc[pt][r] + bq[r];
                    float e   = __expf(tv);
                    Zt[pt] += e;
                    St[pt]  = fmaf(e, tv,  St[pt]);
                    Dd[pt]  = fmaf(e, s1v, Dd[pt]);
                    Zs[pt] += __expf(s1v);
                }
            }

            if (pf) {
                #pragma unroll
                for (int ii = 0; ii < 4; ii++) t4[ii] = t4n[ii];
            }
        }

        // ---- merge 16 partitions per pixel, write per-pixel partials ----
        __syncthreads();
        {
            int part = wv * 4 + q;
            #pragma unroll
            for (int pt = 0; pt < 4; pt++) {
                f32x4 v = {Zt[pt], St[pt], Dd[pt], Zs[pt]};
                *(f32x4*)&scr[(pt * 16 + n) * 68 + part * 4] = v;
            }
        }
        __syncthreads();
        if (tid < 64) {
            float Z = 0.f, S = 0.f, D = 0.f, Z2 = 0.f;
            #pragma unroll
            for (int p = 0; p < 16; p++) {
                const float* s4 = &scr[tid * 68 + p * 4];
                Z += s4[0]; S += s4[1]; D += s4[2]; Z2 += s4[3];
            }
            f32x4 v = {Z, S, D, Z2};
            *(f32x4*)&ws[WS_PIX + half * PIXHALF + ((size_t)b * 4288 + tile * 64 + tid) * 4] = v;
        }
    } else {
        // ---- rowstats role ----
        float* red = (float*)lds;
        int row  = bx - 1072;
        int side = (row >= 152) ? 1 : 0;
        int r    = side ? row - 152 : row;
        const float* src = side ? (t_logit + r * 4225) : (s_logit + r * 16641);

        float z = 0.f, s = 0.f;
        for (int k = tid; k < 16641; k += 256) {
            float v = side ? t_resized(src, k) : src[k];
            float e = __expf(v);
            z += e;
            s = fmaf(e, v, s);
        }
        for (int off = 32; off > 0; off >>= 1) { z += __shfl_down(z, off); s += __shfl_down(s, off); }
        if ((tid & 63) == 0) { red[tid >> 6] = z; red[4 + (tid >> 6)] = s; }
        __syncthreads();
        if (tid == 0) {
            float Z = red[0] + red[1] + red[2] + red[3];
            float S = red[4] + red[5] + red[6] + red[7];
            ws[WS_Z + row] = Z;
            atomicAdd(&ws[(side ? WS_E1 : WS_E0) + (r % 19)], S / Z - logf(Z));
        }
    }
}

// ---------------- mid: Gram (blocks 0..527) + pi finalize (528..661) ----------------
#define KT 512
#define KP 516
__global__ void k_mid(const float* __restrict__ s_logit, const float* __restrict__ t_logit,
                      float* __restrict__ ws, float* __restrict__ out) {
    __shared__ __align__(16) char lds[39296];
    const int tid = threadIdx.x;
    const int bx  = blockIdx.x;

    if (bx < 528) {
        float* pbuf  = (float*)lds;
        float* rowiz = (float*)(lds + 39216);
        int side = (bx >= 264) ? 1 : 0;
        int rm   = side ? bx - 264 : bx;
        int b = rm / 33, kt = rm - b * 33;
        int k0 = kt * KT;

        if (tid < 19) rowiz[tid] = 1.0f / ws[WS_Z + side * 152 + b * 19 + tid];
        __syncthreads();

        for (int i = 0; i < 19; i++) {
            const float* src = side ? (t_logit + (b * 19 + i) * 4225) : (s_logit + (b * 19 + i) * 16641);
            float iz = rowiz[i];
            for (int kl = tid; kl < KT; kl += 256) {
                int k = k0 + kl;
                float p = 0.f;
                if (k < 16641) {
                    float v = side ? t_resized(src, k) : src[k];
                    p = __expf(v) * iz;
                }
                pbuf[i * KP + kl] = p;
            }
        }
        __syncthreads();

        if (tid < 190) {
            int t = tid, i = 0;
            while (t >= 19 - i) { t -= 19 - i; i++; }
            int j = i + t;
            const float* pi_ = &pbuf[i * KP];
            const float* pj_ = &pbuf[j * KP];
            float g = 0.f;
            #pragma unroll 4
            for (int kl = 0; kl < KT; kl += 4) {
                float4 a = *(const float4*)&pi_[kl];
                float4 c = *(const float4*)&pj_[kl];
                g = fmaf(a.x, c.x, g); g = fmaf(a.y, c.y, g);
                g = fmaf(a.z, c.z, g); g = fmaf(a.w, c.w, g);
            }
            atomicAdd(&ws[(side ? WS_G1 : WS_G0) + i * 19 + j], g);
        }
    } else {
        // pi finalize: one thread per padded pixel
        float* red = (float*)lds;
        int gp = (bx - 528) * 256 + tid;      // 0..34303
        int b  = gp / 4288;
        int tp = gp - b * 4288;
        f32x4 a = *(const f32x4*)&ws[WS_PIX + (size_t)gp * 4];
        f32x4 c = *(const f32x4*)&ws[WS_PIX + PIXHALF + (size_t)gp * 4];
        float Z = a[0] + c[0], S = a[1] + c[1], D = a[2] + c[2], Z2 = a[3] + c[3];
        float contrib = (tp < 4225) ? ((S - D) / Z - logf(Z) + logf(Z2)) : 0.f;
        for (int off = 32; off > 0; off >>= 1) contrib += __shfl_down(contrib, off);
        if ((tid & 63) == 0) red[tid >> 6] = contrib;
        __syncthreads();
        if (tid == 0)
            atomicAdd(out, (red[0] + red[1] + red[2] + red[3]) * (1.0f / 25958400.0f));
    }
}

// ---------------- finalize lo_loss (1 block, 384 threads) ----------------
__global__ void k_final(const float* __restrict__ ws, float* __restrict__ out) {
    __shared__ float Ms[361], Mt[361], ns[19], nt[19];
    __shared__ float red[8];
    int tid = threadIdx.x;
    if (tid < 361) {
        int i = tid / 19, j = tid - i * 19;
        int lo = min(i, j), hi = max(i, j);
        Ms[tid] = (ws[WS_E0 + hi] - ws[WS_G0 + lo * 19 + hi]) * 0.125f;
        Mt[tid] = (ws[WS_E1 + hi] - ws[WS_G1 + lo * 19 + hi]) * 0.125f;
    }
    __syncthreads();
    if (tid < 19) {
        float as = 0.f, at = 0.f;
        for (int j = 0; j < 19; j++) {
            as = fmaf(Ms[tid * 19 + j], Ms[tid * 19 + j], as);
            at = fmaf(Mt[tid * 19 + j], Mt[tid * 19 + j], at);
        }
        ns[tid] = fmaxf(sqrtf(as), 1e-12f);
        nt[tid] = fmaxf(sqrtf(at), 1e-12f);
    }
    __syncthreads();
    float d = 0.f;
    if (tid < 361) {
        int i = tid / 19;
        float v = Ms[tid] / ns[i] - Mt[tid] / nt[i];
        d = v * v;
    }
    for (int off = 32; off > 0; off >>= 1) d += __shfl_down(d, off);
    if ((tid & 63) == 0) red[tid >> 6] = d;
    __syncthreads();
    if (tid == 0) out[1] = red[0] + red[1] + red[2] + red[3] + red[4] + red[5];
}

extern "C" void kernel_launch(void* const* d_in, const int* in_sizes, int n_in,
                              void* d_out, int out_size, void* d_ws, size_t ws_size,
                              hipStream_t stream) {
    const float* s_out   = (const float*)d_in[0];
    const float* t_out   = (const float*)d_in[1];
    const float* t_logit = (const float*)d_in[2];
    const float* s_logit = (const float*)d_in[3];
    const float* conv_w  = (const float*)d_in[4];
    const float* conv_b  = (const float*)d_in[5];
    float* out = (float*)d_out;
    float* ws  = (float*)d_ws;

    k_init<<<dim3(64), dim3(256), 0, stream>>>(conv_w, ws, out);
    k_main<<<dim3(1376), dim3(256), 0, stream>>>(s_out, t_out, conv_b, s_logit, t_logit, ws, out);
    k_mid<<<dim3(662), dim3(256), 0, stream>>>(s_logit, t_logit, ws, out);
    k_final<<<dim3(1), dim3(384), 0, stream>>>(ws, out);
}